// Round 6
// baseline (116.891 us; speedup 1.0000x reference)
//
#include <hip/hip_runtime.h>
#include <math.h>

#define M_   2049
#define B_   16
#define N_   1024
#define TAU_ 2.821e-5
#define PI_  3.14159265358979323846
#define TWO_PI_ 6.283185307179586476925286766559

#define GS_CH    8      // point-chunks per batch in the scatter spread
#define H_JSPLIT 16     // j-split for h part (chunks of 64 over j=1..1024)
#define CV_SPLIT 16     // mp-split for conv_kernel
#define FMM_LPP  16     // lanes per point in fmm_kernel

// ---------------------------------------------------------------------------
// Fused kernel 1:
//  blocks [0, GS_CH*B_):      gsum scatter — each point adds its 68-bin
//    Gaussian window into LDS bins (ds atomics), then one drain of global
//    f64 atomics.
//  blocks [GS_CH*B_, +5*H_JSPLIT): h kernel, BOTH channels per block —
//    hhalf[c][d] = (1/M)(W0 + 2 sum_j Wj cos(2pi j d/M)) via mirrored LDS
//    cos table + exact incremental (j*d) mod M; j-split, atomicAdd into
//    pre-zeroed hhalf.
// ---------------------------------------------------------------------------
__global__ void spread_h_kernel(const float* __restrict__ x,
                                const float* __restrict__ s0, const float* __restrict__ a0,
                                const float* __restrict__ s1, const float* __restrict__ a1,
                                double* __restrict__ gsum, double* __restrict__ hhalf) {
    __shared__ double smem[M_ + 128];
    const int bx = blockIdx.x;

    if (bx < GS_CH * B_) {
        // ---- gsum scatter part ----
        const int b  = bx / GS_CH;
        const int ch = bx % GS_CH;
        for (int i = threadIdx.x; i < M_; i += 256) smem[i] = 0.0;
        __syncthreads();
        const int pl  = threadIdx.x >> 1;          // local point 0..127
        const int sub = threadIdx.x & 1;           // half-window 0/1
        const double du      = TWO_PI_ / (double)M_;
        const double inv4tau = 1.0 / (4.0 * TAU_);
        const double u = (double)x[b * N_ + ch * (N_ / GS_CH) + pl] * (TWO_PI_ / 10.0);
        const int mc = (int)(u / du + 0.5);
        const int start = mc - 33 + sub * 34;      // covers mc-33 .. mc+34
        for (int i = 0; i < 34; ++i) {
            int m = start + i;
            if (m >= 0 && m < M_) {
                double d = u - du * (double)m;
                double t = d * d * inv4tau;
                if (t < 88.0) atomicAdd(&smem[m], (double)__expf(-(float)t));
            }
        }
        __syncthreads();
        for (int i = threadIdx.x; i < M_; i += 256) {
            double v = smem[i];
            if (v != 0.0) atomicAdd(&gsum[b * M_ + i], v);
        }
    } else {
        // ---- h part (both channels) ----
        const int t  = bx - GS_CH * B_;
        const int dt = t % 5;                      // d-tile 0..4
        const int jc = t / 5;                      // j-chunk 0..H_JSPLIT-1
        double* costab = smem;                     // 2049
        double* cf0    = smem + M_;                // 64
        double* cf1    = smem + M_ + 64;           // 64
        const int jlo = 1 + jc * (1024 / H_JSPLIT);
        const double ang0 = TWO_PI_ / (double)M_;

        // mirrored cos table: cos(2pi (M-i)/M) = cos(2pi i/M)
        for (int i = threadIdx.x; i <= 1024; i += 256) {
            double v = cos(ang0 * (double)i);
            costab[i] = v;
            if (i > 0) costab[M_ - i] = v;
        }
        if (threadIdx.x < 1024 / H_JSPLIT) {
            int j = jlo + threadIdx.x;
            double k2   = (double)j * (double)j;
            double dec2 = (PI_ / TAU_) * exp(2.0 * TAU_ * k2);   // deconv^2
            double base = 2.0 * (10.0 / TWO_PI_) * dec2 / (double)M_;
            double sA = 5.0 * (double)s0[0];
            cf0[threadIdx.x] = base * (-(double)a0[0] * 4.0 * PI_ / (k2 + sA * sA));
            double sB = 5.0 * (double)s1[0];
            double den = k2 + sB * sB;
            cf1[threadIdx.x] = base * ((double)a1[0] * 4.0 * PI_ / (den * den));
        }
        __syncthreads();

        const int d = dt * 256 + threadIdx.x;
        if (d > 1024) return;

        double acc0 = 0.0, acc1 = 0.0;
        if (jc == 0) {   // j = 0 term, added once per channel
            double w0base = (10.0 / TWO_PI_) * (PI_ / TAU_) / (double)M_;
            double sA = 5.0 * (double)s0[0];
            acc0 = w0base * (-(double)a0[0] * 4.0 * PI_ / (sA * sA));
            double sB = 5.0 * (double)s1[0];
            acc1 = w0base * ((double)a1[0] * 4.0 * PI_ / ((sB * sB) * (sB * sB)));
        }
        int r = (int)(((long long)jlo * (long long)d) % M_);
        #pragma unroll 4
        for (int jj = 0; jj < 1024 / H_JSPLIT; ++jj) {
            double cv_ = costab[r];
            acc0 += cf0[jj] * cv_;
            acc1 += cf1[jj] * cv_;
            r += d; if (r >= M_) r -= M_;
        }
        atomicAdd(&hhalf[d], acc0);
        atomicAdd(&hhalf[1025 + d], acc1);
    }
}

// ---------------------------------------------------------------------------
// conv[b][c][m] += sum over this block's mp-chunk of gsum[b][mp]*h_c[(m-mp) mod M]
// FIR register-sliding-window: each lane computes R=4 consecutive m for both
// channels; per tap only 1 new LDS read per channel (8 FMAs per 2 reads).
// m-tiles: mt in {0,1} cover m 0..2047; m=2048 handled by a parallel
// reduction in mt==1 blocks (window already staged).  mp split CV_SPLIT ways;
// f64 atomicAdd into pre-zeroed conv.
// ---------------------------------------------------------------------------
__global__ void conv_kernel(const double* __restrict__ gsum, const double* __restrict__ hhalf,
                            double* __restrict__ conv) {
    __shared__ double w0s[1160];
    __shared__ double w1s[1160];
    __shared__ double red[512];
    const int mt = blockIdx.x;          // 0 or 1
    const int s  = blockIdx.y;          // mp-chunk
    const int b  = blockIdx.z;
    const int m0  = mt * 1024;
    const int p0  = (s * M_) / CV_SPLIT;
    const int p1  = ((s + 1) * M_) / CV_SPLIT;
    const int len = p1 - p0;            // 128 or 129
    const int wcount = 1024 + len;      // window covers m in [m0, m0+1024]
    int base = m0 - (p0 + len - 1);     // i_min
    while (base < 0) base += M_;
    for (int i = threadIdx.x; i < wcount; i += 256) {
        int idx = base + i;
        while (idx >= M_) idx -= M_;
        int d = (idx > 1024) ? (M_ - idx) : idx;   // h even: h[d] = hhalf[min(d,M-d)]
        w0s[i] = hhalf[d];
        w1s[i] = hhalf[1025 + d];
    }
    __syncthreads();

    const double* gs = gsum + (size_t)b * M_ + p0;   // wave-uniform -> scalar loads

    // main chains: m = m0 + 4*tid + r, r=0..3
    int q = 4 * threadIdx.x + len - 1;
    double c0w0 = w0s[q],     c0w1 = w0s[q + 1], c0w2 = w0s[q + 2], c0w3 = w0s[q + 3];
    double c1w0 = w1s[q],     c1w1 = w1s[q + 1], c1w2 = w1s[q + 2], c1w3 = w1s[q + 3];
    double a00 = 0.0, a01 = 0.0, a02 = 0.0, a03 = 0.0;
    double a10 = 0.0, a11 = 0.0, a12 = 0.0, a13 = 0.0;
    #pragma unroll 4
    for (int t = 0; t < len; ++t) {
        double g = gs[t];
        a00 += g * c0w0; a01 += g * c0w1; a02 += g * c0w2; a03 += g * c0w3;
        a10 += g * c1w0; a11 += g * c1w1; a12 += g * c1w2; a13 += g * c1w3;
        // slide window down by one (next tap uses indices one lower)
        c0w3 = c0w2; c0w2 = c0w1; c0w1 = c0w0;
        c1w3 = c1w2; c1w2 = c1w1; c1w1 = c1w0;
        --q;
        c0w0 = w0s[q]; c1w0 = w1s[q];
    }
    {
        double* cv = conv + (size_t)(b * 2) * M_ + m0 + 4 * threadIdx.x;
        atomicAdd(cv + 0,      a00); atomicAdd(cv + 1,      a01);
        atomicAdd(cv + 2,      a02); atomicAdd(cv + 3,      a03);
        atomicAdd(cv + M_ + 0, a10); atomicAdd(cv + M_ + 1, a11);
        atomicAdd(cv + M_ + 2, a12); atomicAdd(cv + M_ + 3, a13);
    }

    // m = 2048 side-reduction (mt==1 blocks only; window covers q=1023+len-tid)
    double t0 = 0.0, t1 = 0.0;
    if (mt == 1 && threadIdx.x < len) {
        double g = gs[threadIdx.x];
        int qq = 1023 + len - threadIdx.x;
        t0 = g * w0s[qq];
        t1 = g * w1s[qq];
    }
    red[threadIdx.x]       = t0;
    red[256 + threadIdx.x] = t1;
    __syncthreads();
    for (int off = 128; off > 0; off >>= 1) {
        if (threadIdx.x < off) {
            red[threadIdx.x]       += red[threadIdx.x + off];
            red[256 + threadIdx.x] += red[256 + threadIdx.x + off];
        }
        __syncthreads();
    }
    if (mt == 1 && threadIdx.x == 0) {
        double* cv = conv + (size_t)(b * 2) * M_;
        atomicAdd(cv + 2048,      red[0]);
        atomicAdd(cv + M_ + 2048, red[256]);
    }
}

// ---------------------------------------------------------------------------
// fmm[b][n][c] = (1/M) sum_m g[b,n,m] * conv[b][c][m]
// FMM_LPP lanes per point; contiguous window reads; shfl-xor reduce.
// ---------------------------------------------------------------------------
__global__ void fmm_kernel(const float* __restrict__ x, const double* __restrict__ conv,
                           float* __restrict__ out) {
    const int gid = blockIdx.x * 256 + threadIdx.x;
    const int pt  = gid / FMM_LPP;     // point id = b*N + n
    const int sub = gid % FMM_LPP;
    const int b   = pt >> 10;          // / N_
    const double du      = TWO_PI_ / (double)M_;
    const double inv4tau = 1.0 / (4.0 * TAU_);
    const double u = (double)x[pt] * (TWO_PI_ / 10.0);
    int mc = (int)(u / du + 0.5);
    int lo = mc - 34; if (lo < 0) lo = 0;
    int hi = mc + 34; if (hi > M_ - 1) hi = M_ - 1;
    const double* c0 = conv + (size_t)(b * 2) * M_;
    const double* c1 = c0 + M_;
    double a0 = 0.0, a1 = 0.0;
    for (int m = lo + sub; m <= hi; m += FMM_LPP) {
        double d = u - du * (double)m;
        double g = (double)__expf(-(float)(d * d * inv4tau));
        a0 += g * c0[m];
        a1 += g * c1[m];
    }
    a0 += __shfl_xor(a0, 1); a1 += __shfl_xor(a1, 1);
    a0 += __shfl_xor(a0, 2); a1 += __shfl_xor(a1, 2);
    a0 += __shfl_xor(a0, 4); a1 += __shfl_xor(a1, 4);
    a0 += __shfl_xor(a0, 8); a1 += __shfl_xor(a1, 8);
    if (sub == 0) {
        out[pt * 2 + 0] = (float)(a0 / (double)M_);
        out[pt * 2 + 1] = (float)(a1 / (double)M_);
    }
}

// ---------------------------------------------------------------------------
extern "C" void kernel_launch(void* const* d_in, const int* in_sizes, int n_in,
                              void* d_out, int out_size, void* d_ws, size_t ws_size,
                              hipStream_t stream) {
    (void)in_sizes; (void)n_in; (void)out_size; (void)ws_size;
    const float* x  = (const float*)d_in[0];
    const float* s0 = (const float*)d_in[1];
    const float* a0 = (const float*)d_in[2];
    const float* s1 = (const float*)d_in[3];
    const float* a1 = (const float*)d_in[4];
    float* out = (float*)d_out;

    // Workspace layout (f64, contiguous): [gsum B*M | hhalf 2*1025 | conv B*2*M]
    double* gsum  = (double*)d_ws;             // 32784
    double* hhalf = gsum + B_ * M_;            // 2050
    double* conv  = hhalf + 2 * 1025;          // 65568

    // Zero all atomic-accumulated regions in one shot (~803 KB)
    hipMemsetAsync(d_ws, 0, (size_t)(B_ * M_ + 2 * 1025 + B_ * 2 * M_) * sizeof(double), stream);

    hipLaunchKernelGGL(spread_h_kernel, dim3(GS_CH * B_ + 5 * H_JSPLIT), dim3(256), 0,
                       stream, x, s0, a0, s1, a1, gsum, hhalf);
    hipLaunchKernelGGL(conv_kernel, dim3(2, CV_SPLIT, B_), dim3(256), 0, stream,
                       gsum, hhalf, conv);
    hipLaunchKernelGGL(fmm_kernel, dim3(B_ * N_ * FMM_LPP / 256), dim3(256), 0, stream,
                       x, conv, out);
}

// Round 7
// 107.796 us; speedup vs baseline: 1.0844x; 1.0844x over previous
//
#include <hip/hip_runtime.h>
#include <math.h>

#define M_   2049
#define B_   16
#define N_   1024
#define TAU_ 2.821e-5
#define PI_  3.14159265358979323846
#define TWO_PI_ 6.283185307179586476925286766559

#define GS_CH    8      // point-chunks per batch in the scatter spread
#define H_JSPLIT 16     // j-split for h part (chunks of 64 over j=1..1024)
#define CV_SPLIT 16     // mp-split for conv_kernel
#define FMM_LPP  16     // lanes per point in fmm_kernel

// LDS swizzle for the conv h-window: pad 1 double per 4 so that the FIR
// lane-stride-4 read pattern (word stride 8 -> 16-way bank conflict raw)
// becomes word stride 10 -> 16 bank pairs over 64 lanes = 4-way (~free).
#define SW(i) ((i) + ((i) >> 2))

// ---------------------------------------------------------------------------
// Fused kernel 1:
//  blocks [0, GS_CH*B_):      gsum scatter — each point adds its 68-bin
//    Gaussian window into LDS bins (ds atomics), then one drain of global
//    f64 atomics.
//  blocks [GS_CH*B_, +5*H_JSPLIT): h kernel, BOTH channels per block —
//    hhalf[c][d] = (1/M)(W0 + 2 sum_j Wj cos(2pi j d/M)) via mirrored LDS
//    cos table + exact incremental (j*d) mod M; j-split, atomicAdd into
//    pre-zeroed hhalf.
// ---------------------------------------------------------------------------
__global__ void spread_h_kernel(const float* __restrict__ x,
                                const float* __restrict__ s0, const float* __restrict__ a0,
                                const float* __restrict__ s1, const float* __restrict__ a1,
                                double* __restrict__ gsum, double* __restrict__ hhalf) {
    __shared__ double smem[M_ + 128];
    const int bx = blockIdx.x;

    if (bx < GS_CH * B_) {
        // ---- gsum scatter part ----
        const int b  = bx / GS_CH;
        const int ch = bx % GS_CH;
        for (int i = threadIdx.x; i < M_; i += 256) smem[i] = 0.0;
        __syncthreads();
        const int pl  = threadIdx.x >> 1;          // local point 0..127
        const int sub = threadIdx.x & 1;           // half-window 0/1
        const double du      = TWO_PI_ / (double)M_;
        const double inv4tau = 1.0 / (4.0 * TAU_);
        const double u = (double)x[b * N_ + ch * (N_ / GS_CH) + pl] * (TWO_PI_ / 10.0);
        const int mc = (int)(u / du + 0.5);
        const int start = mc - 33 + sub * 34;      // covers mc-33 .. mc+34
        for (int i = 0; i < 34; ++i) {
            int m = start + i;
            if (m >= 0 && m < M_) {
                double d = u - du * (double)m;
                double t = d * d * inv4tau;
                if (t < 88.0) atomicAdd(&smem[m], (double)__expf(-(float)t));
            }
        }
        __syncthreads();
        for (int i = threadIdx.x; i < M_; i += 256) {
            double v = smem[i];
            if (v != 0.0) atomicAdd(&gsum[b * M_ + i], v);
        }
    } else {
        // ---- h part (both channels) ----
        const int t  = bx - GS_CH * B_;
        const int dt = t % 5;                      // d-tile 0..4
        const int jc = t / 5;                      // j-chunk 0..H_JSPLIT-1
        double* costab = smem;                     // 2049
        double* cf0    = smem + M_;                // 64
        double* cf1    = smem + M_ + 64;           // 64
        const int jlo = 1 + jc * (1024 / H_JSPLIT);
        const double ang0 = TWO_PI_ / (double)M_;

        // mirrored cos table: cos(2pi (M-i)/M) = cos(2pi i/M)
        for (int i = threadIdx.x; i <= 1024; i += 256) {
            double v = cos(ang0 * (double)i);
            costab[i] = v;
            if (i > 0) costab[M_ - i] = v;
        }
        if (threadIdx.x < 1024 / H_JSPLIT) {
            int j = jlo + threadIdx.x;
            double k2   = (double)j * (double)j;
            double dec2 = (PI_ / TAU_) * exp(2.0 * TAU_ * k2);   // deconv^2
            double base = 2.0 * (10.0 / TWO_PI_) * dec2 / (double)M_;
            double sA = 5.0 * (double)s0[0];
            cf0[threadIdx.x] = base * (-(double)a0[0] * 4.0 * PI_ / (k2 + sA * sA));
            double sB = 5.0 * (double)s1[0];
            double den = k2 + sB * sB;
            cf1[threadIdx.x] = base * ((double)a1[0] * 4.0 * PI_ / (den * den));
        }
        __syncthreads();

        const int d = dt * 256 + threadIdx.x;
        if (d > 1024) return;

        double acc0 = 0.0, acc1 = 0.0;
        if (jc == 0) {   // j = 0 term, added once per channel
            double w0base = (10.0 / TWO_PI_) * (PI_ / TAU_) / (double)M_;
            double sA = 5.0 * (double)s0[0];
            acc0 = w0base * (-(double)a0[0] * 4.0 * PI_ / (sA * sA));
            double sB = 5.0 * (double)s1[0];
            acc1 = w0base * ((double)a1[0] * 4.0 * PI_ / ((sB * sB) * (sB * sB)));
        }
        int r = (int)(((long long)jlo * (long long)d) % M_);
        #pragma unroll 4
        for (int jj = 0; jj < 1024 / H_JSPLIT; ++jj) {
            double cv_ = costab[r];
            acc0 += cf0[jj] * cv_;
            acc1 += cf1[jj] * cv_;
            r += d; if (r >= M_) r -= M_;
        }
        atomicAdd(&hhalf[d], acc0);
        atomicAdd(&hhalf[1025 + d], acc1);
    }
}

// ---------------------------------------------------------------------------
// conv[b][c][m] += sum over this block's mp-chunk of gsum[b][mp]*h_c[(m-mp) mod M]
// FIR register-sliding-window, SWIZZLED window storage (see SW): each lane
// computes R=4 consecutive m for both channels; per tap 1 new LDS read per
// channel serves 8 FMAs, at 4-way (near-free) bank aliasing.
// m-tiles: mt in {0,1} cover m 0..2047; m=2048 via parallel reduction in
// mt==1 blocks.  mp split CV_SPLIT ways; f64 atomicAdd into pre-zeroed conv.
// ---------------------------------------------------------------------------
__global__ void conv_kernel(const double* __restrict__ gsum, const double* __restrict__ hhalf,
                            double* __restrict__ conv) {
    __shared__ double w0s[1456];        // SW(1152) = 1440 max
    __shared__ double w1s[1456];
    __shared__ double red[512];
    const int mt = blockIdx.x;          // 0 or 1
    const int s  = blockIdx.y;          // mp-chunk
    const int b  = blockIdx.z;
    const int m0  = mt * 1024;
    const int p0  = (s * M_) / CV_SPLIT;
    const int p1  = ((s + 1) * M_) / CV_SPLIT;
    const int len = p1 - p0;            // 128 or 129
    const int wcount = 1024 + len;      // window covers m in [m0, m0+1024]
    int base = m0 - (p0 + len - 1);     // i_min
    while (base < 0) base += M_;
    for (int i = threadIdx.x; i < wcount; i += 256) {
        int idx = base + i;
        while (idx >= M_) idx -= M_;
        int d = (idx > 1024) ? (M_ - idx) : idx;   // h even: h[d] = hhalf[min(d,M-d)]
        w0s[SW(i)] = hhalf[d];
        w1s[SW(i)] = hhalf[1025 + d];
    }
    __syncthreads();

    const double* gs = gsum + (size_t)b * M_ + p0;   // wave-uniform -> scalar loads

    // main chains: m = m0 + 4*tid + r, r=0..3
    int q = 4 * threadIdx.x + len - 1;
    double c0w0 = w0s[SW(q)],   c0w1 = w0s[SW(q+1)], c0w2 = w0s[SW(q+2)], c0w3 = w0s[SW(q+3)];
    double c1w0 = w1s[SW(q)],   c1w1 = w1s[SW(q+1)], c1w2 = w1s[SW(q+2)], c1w3 = w1s[SW(q+3)];
    double a00 = 0.0, a01 = 0.0, a02 = 0.0, a03 = 0.0;
    double a10 = 0.0, a11 = 0.0, a12 = 0.0, a13 = 0.0;
    #pragma unroll 4
    for (int t = 0; t < len; ++t) {
        double g = gs[t];
        a00 += g * c0w0; a01 += g * c0w1; a02 += g * c0w2; a03 += g * c0w3;
        a10 += g * c1w0; a11 += g * c1w1; a12 += g * c1w2; a13 += g * c1w3;
        // slide window down by one (next tap uses indices one lower)
        c0w3 = c0w2; c0w2 = c0w1; c0w1 = c0w0;
        c1w3 = c1w2; c1w2 = c1w1; c1w1 = c1w0;
        --q;
        c0w0 = w0s[SW(q)]; c1w0 = w1s[SW(q)];
    }
    {
        double* cv = conv + (size_t)(b * 2) * M_ + m0 + 4 * threadIdx.x;
        atomicAdd(cv + 0,      a00); atomicAdd(cv + 1,      a01);
        atomicAdd(cv + 2,      a02); atomicAdd(cv + 3,      a03);
        atomicAdd(cv + M_ + 0, a10); atomicAdd(cv + M_ + 1, a11);
        atomicAdd(cv + M_ + 2, a12); atomicAdd(cv + M_ + 3, a13);
    }

    // m = 2048 side-reduction (mt==1 blocks only; window covers qq)
    double t0 = 0.0, t1 = 0.0;
    if (mt == 1 && threadIdx.x < len) {
        double g = gs[threadIdx.x];
        int qq = 1023 + len - threadIdx.x;
        t0 = g * w0s[SW(qq)];
        t1 = g * w1s[SW(qq)];
    }
    red[threadIdx.x]       = t0;
    red[256 + threadIdx.x] = t1;
    __syncthreads();
    for (int off = 128; off > 0; off >>= 1) {
        if (threadIdx.x < off) {
            red[threadIdx.x]       += red[threadIdx.x + off];
            red[256 + threadIdx.x] += red[256 + threadIdx.x + off];
        }
        __syncthreads();
    }
    if (mt == 1 && threadIdx.x == 0) {
        double* cv = conv + (size_t)(b * 2) * M_;
        atomicAdd(cv + 2048,      red[0]);
        atomicAdd(cv + M_ + 2048, red[256]);
    }
}

// ---------------------------------------------------------------------------
// fmm[b][n][c] = (1/M) sum_m g[b,n,m] * conv[b][c][m]
// FMM_LPP lanes per point; contiguous window reads; shfl-xor reduce.
// ---------------------------------------------------------------------------
__global__ void fmm_kernel(const float* __restrict__ x, const double* __restrict__ conv,
                           float* __restrict__ out) {
    const int gid = blockIdx.x * 256 + threadIdx.x;
    const int pt  = gid / FMM_LPP;     // point id = b*N + n
    const int sub = gid % FMM_LPP;
    const int b   = pt >> 10;          // / N_
    const double du      = TWO_PI_ / (double)M_;
    const double inv4tau = 1.0 / (4.0 * TAU_);
    const double u = (double)x[pt] * (TWO_PI_ / 10.0);
    int mc = (int)(u / du + 0.5);
    int lo = mc - 34; if (lo < 0) lo = 0;
    int hi = mc + 34; if (hi > M_ - 1) hi = M_ - 1;
    const double* c0 = conv + (size_t)(b * 2) * M_;
    const double* c1 = c0 + M_;
    double a0 = 0.0, a1 = 0.0;
    for (int m = lo + sub; m <= hi; m += FMM_LPP) {
        double d = u - du * (double)m;
        double g = (double)__expf(-(float)(d * d * inv4tau));
        a0 += g * c0[m];
        a1 += g * c1[m];
    }
    a0 += __shfl_xor(a0, 1); a1 += __shfl_xor(a1, 1);
    a0 += __shfl_xor(a0, 2); a1 += __shfl_xor(a1, 2);
    a0 += __shfl_xor(a0, 4); a1 += __shfl_xor(a1, 4);
    a0 += __shfl_xor(a0, 8); a1 += __shfl_xor(a1, 8);
    if (sub == 0) {
        out[pt * 2 + 0] = (float)(a0 / (double)M_);
        out[pt * 2 + 1] = (float)(a1 / (double)M_);
    }
}

// ---------------------------------------------------------------------------
extern "C" void kernel_launch(void* const* d_in, const int* in_sizes, int n_in,
                              void* d_out, int out_size, void* d_ws, size_t ws_size,
                              hipStream_t stream) {
    (void)in_sizes; (void)n_in; (void)out_size; (void)ws_size;
    const float* x  = (const float*)d_in[0];
    const float* s0 = (const float*)d_in[1];
    const float* a0 = (const float*)d_in[2];
    const float* s1 = (const float*)d_in[3];
    const float* a1 = (const float*)d_in[4];
    float* out = (float*)d_out;

    // Workspace layout (f64, contiguous): [gsum B*M | hhalf 2*1025 | conv B*2*M]
    double* gsum  = (double*)d_ws;             // 32784
    double* hhalf = gsum + B_ * M_;            // 2050
    double* conv  = hhalf + 2 * 1025;          // 65568

    // Zero all atomic-accumulated regions in one shot (~803 KB)
    hipMemsetAsync(d_ws, 0, (size_t)(B_ * M_ + 2 * 1025 + B_ * 2 * M_) * sizeof(double), stream);

    hipLaunchKernelGGL(spread_h_kernel, dim3(GS_CH * B_ + 5 * H_JSPLIT), dim3(256), 0,
                       stream, x, s0, a0, s1, a1, gsum, hhalf);
    hipLaunchKernelGGL(conv_kernel, dim3(2, CV_SPLIT, B_), dim3(256), 0, stream,
                       gsum, hhalf, conv);
    hipLaunchKernelGGL(fmm_kernel, dim3(B_ * N_ * FMM_LPP / 256), dim3(256), 0, stream,
                       x, conv, out);
}

// Round 8
// 90.945 us; speedup vs baseline: 1.2853x; 1.1853x over previous
//
#include <hip/hip_runtime.h>
#include <math.h>

#define M_   2049
#define B_   16
#define N_   1024
#define TAU_ 2.821e-5
#define PI_  3.14159265358979323846
#define TWO_PI_ 6.283185307179586476925286766559

#define GS_CH    8      // point-chunks per batch in the scatter spread
#define H_JSPLIT 16     // j-split for h part (chunks of 64 over j=1..1024)
#define CV_SPLIT 16     // mp-split for conv_kernel
#define FMM_LPP  16     // lanes per point in fmm_kernel
#define MPAD     2052   // padded m-stride for conv partials (multiple of 4)

// LDS swizzle for the conv h-window: pad 1 double per 4 so that the FIR
// lane-stride-4 read pattern (word stride 8 -> 16-way bank conflict raw)
// becomes word stride 10 -> 4-way aliasing (~free).  [R7: conflicts 6.4M->76K]
#define SW(i) ((i) + ((i) >> 2))

// ---------------------------------------------------------------------------
// Fused kernel 1:
//  blocks [0, GS_CH*B_):      gsum scatter via LDS bins + global f64 drain.
//  blocks [GS_CH*B_, +5*H_JSPLIT): h kernel, both channels per block.
// ---------------------------------------------------------------------------
__global__ void spread_h_kernel(const float* __restrict__ x,
                                const float* __restrict__ s0, const float* __restrict__ a0,
                                const float* __restrict__ s1, const float* __restrict__ a1,
                                double* __restrict__ gsum, double* __restrict__ hhalf) {
    __shared__ double smem[M_ + 128];
    const int bx = blockIdx.x;

    if (bx < GS_CH * B_) {
        // ---- gsum scatter part ----
        const int b  = bx / GS_CH;
        const int ch = bx % GS_CH;
        for (int i = threadIdx.x; i < M_; i += 256) smem[i] = 0.0;
        __syncthreads();
        const int pl  = threadIdx.x >> 1;          // local point 0..127
        const int sub = threadIdx.x & 1;           // half-window 0/1
        const double du      = TWO_PI_ / (double)M_;
        const double inv4tau = 1.0 / (4.0 * TAU_);
        const double u = (double)x[b * N_ + ch * (N_ / GS_CH) + pl] * (TWO_PI_ / 10.0);
        const int mc = (int)(u / du + 0.5);
        const int start = mc - 33 + sub * 34;      // covers mc-33 .. mc+34
        for (int i = 0; i < 34; ++i) {
            int m = start + i;
            if (m >= 0 && m < M_) {
                double d = u - du * (double)m;
                double t = d * d * inv4tau;
                if (t < 88.0) atomicAdd(&smem[m], (double)__expf(-(float)t));
            }
        }
        __syncthreads();
        for (int i = threadIdx.x; i < M_; i += 256) {
            double v = smem[i];
            if (v != 0.0) atomicAdd(&gsum[b * M_ + i], v);
        }
    } else {
        // ---- h part (both channels) ----
        const int t  = bx - GS_CH * B_;
        const int dt = t % 5;                      // d-tile 0..4
        const int jc = t / 5;                      // j-chunk 0..H_JSPLIT-1
        double* costab = smem;                     // 2049
        double* cf0    = smem + M_;                // 64
        double* cf1    = smem + M_ + 64;           // 64
        const int jlo = 1 + jc * (1024 / H_JSPLIT);
        const double ang0 = TWO_PI_ / (double)M_;

        // mirrored cos table: cos(2pi (M-i)/M) = cos(2pi i/M)
        for (int i = threadIdx.x; i <= 1024; i += 256) {
            double v = cos(ang0 * (double)i);
            costab[i] = v;
            if (i > 0) costab[M_ - i] = v;
        }
        if (threadIdx.x < 1024 / H_JSPLIT) {
            int j = jlo + threadIdx.x;
            double k2   = (double)j * (double)j;
            double dec2 = (PI_ / TAU_) * exp(2.0 * TAU_ * k2);   // deconv^2
            double base = 2.0 * (10.0 / TWO_PI_) * dec2 / (double)M_;
            double sA = 5.0 * (double)s0[0];
            cf0[threadIdx.x] = base * (-(double)a0[0] * 4.0 * PI_ / (k2 + sA * sA));
            double sB = 5.0 * (double)s1[0];
            double den = k2 + sB * sB;
            cf1[threadIdx.x] = base * ((double)a1[0] * 4.0 * PI_ / (den * den));
        }
        __syncthreads();

        const int d = dt * 256 + threadIdx.x;
        if (d > 1024) return;

        double acc0 = 0.0, acc1 = 0.0;
        if (jc == 0) {   // j = 0 term, added once per channel
            double w0base = (10.0 / TWO_PI_) * (PI_ / TAU_) / (double)M_;
            double sA = 5.0 * (double)s0[0];
            acc0 = w0base * (-(double)a0[0] * 4.0 * PI_ / (sA * sA));
            double sB = 5.0 * (double)s1[0];
            acc1 = w0base * ((double)a1[0] * 4.0 * PI_ / ((sB * sB) * (sB * sB)));
        }
        int r = (int)(((long long)jlo * (long long)d) % M_);
        #pragma unroll 4
        for (int jj = 0; jj < 1024 / H_JSPLIT; ++jj) {
            double cv_ = costab[r];
            acc0 += cf0[jj] * cv_;
            acc1 += cf1[jj] * cv_;
            r += d; if (r >= M_) r -= M_;
        }
        atomicAdd(&hhalf[d], acc0);
        atomicAdd(&hhalf[1025 + d], acc1);
    }
}

// ---------------------------------------------------------------------------
// part[s][b][c][m] = sum over mp-chunk s of gsum[b][mp]*h_c[(m-mp) mod M]
// FIR register-sliding-window, swizzled LDS window; R=4 consecutive m per
// lane, both channels.  PLAIN coalesced stores into a private partial slice
// (replaces R7's 16-way-contended device atomics: WRITE 33.5MB -> 8.4MB).
// ---------------------------------------------------------------------------
__global__ void conv_kernel(const double* __restrict__ gsum, const double* __restrict__ hhalf,
                            double* __restrict__ part) {
    __shared__ double w0s[1456];        // SW(1153) max
    __shared__ double w1s[1456];
    __shared__ double red[512];
    const int mt = blockIdx.x;          // 0 or 1
    const int s  = blockIdx.y;          // mp-chunk
    const int b  = blockIdx.z;
    const int m0  = mt * 1024;
    const int p0  = (s * M_) / CV_SPLIT;
    const int p1  = ((s + 1) * M_) / CV_SPLIT;
    const int len = p1 - p0;            // 128 or 129
    const int wcount = 1024 + len;      // window covers m in [m0, m0+1024]
    int base = m0 - (p0 + len - 1);     // i_min
    while (base < 0) base += M_;
    for (int i = threadIdx.x; i < wcount; i += 256) {
        int idx = base + i;
        while (idx >= M_) idx -= M_;
        int d = (idx > 1024) ? (M_ - idx) : idx;   // h even: h[d] = hhalf[min(d,M-d)]
        w0s[SW(i)] = hhalf[d];
        w1s[SW(i)] = hhalf[1025 + d];
    }
    __syncthreads();

    const double* gs = gsum + (size_t)b * M_ + p0;   // wave-uniform -> scalar loads

    // main chains: m = m0 + 4*tid + r, r=0..3
    int q = 4 * threadIdx.x + len - 1;
    double c0w0 = w0s[SW(q)],   c0w1 = w0s[SW(q+1)], c0w2 = w0s[SW(q+2)], c0w3 = w0s[SW(q+3)];
    double c1w0 = w1s[SW(q)],   c1w1 = w1s[SW(q+1)], c1w2 = w1s[SW(q+2)], c1w3 = w1s[SW(q+3)];
    double a00 = 0.0, a01 = 0.0, a02 = 0.0, a03 = 0.0;
    double a10 = 0.0, a11 = 0.0, a12 = 0.0, a13 = 0.0;
    #pragma unroll 4
    for (int t = 0; t < len; ++t) {
        double g = gs[t];
        a00 += g * c0w0; a01 += g * c0w1; a02 += g * c0w2; a03 += g * c0w3;
        a10 += g * c1w0; a11 += g * c1w1; a12 += g * c1w2; a13 += g * c1w3;
        // slide window down by one (next tap uses indices one lower)
        c0w3 = c0w2; c0w2 = c0w1; c0w1 = c0w0;
        c1w3 = c1w2; c1w2 = c1w1; c1w1 = c1w0;
        --q;
        c0w0 = w0s[SW(q)]; c1w0 = w1s[SW(q)];
    }
    {
        double* pv = part + (((size_t)s * B_ + b) * 2) * MPAD + m0 + 4 * threadIdx.x;
        pv[0]        = a00; pv[1]        = a01; pv[2]        = a02; pv[3]        = a03;
        pv[MPAD + 0] = a10; pv[MPAD + 1] = a11; pv[MPAD + 2] = a12; pv[MPAD + 3] = a13;
    }

    // m = 2048 side-reduction — mt==1 blocks only (mt uniform per block)
    if (mt == 1) {
        double t0 = 0.0, t1 = 0.0;
        if (threadIdx.x < len) {
            double g = gs[threadIdx.x];
            int qq = 1023 + len - threadIdx.x;
            t0 = g * w0s[SW(qq)];
            t1 = g * w1s[SW(qq)];
        }
        red[threadIdx.x]       = t0;
        red[256 + threadIdx.x] = t1;
        __syncthreads();
        for (int off = 128; off > 0; off >>= 1) {
            if (threadIdx.x < off) {
                red[threadIdx.x]       += red[threadIdx.x + off];
                red[256 + threadIdx.x] += red[256 + threadIdx.x + off];
            }
            __syncthreads();
        }
        if (threadIdx.x == 0) {
            double* pv = part + (((size_t)s * B_ + b) * 2) * MPAD;
            pv[2048]        = red[0];
            pv[MPAD + 2048] = red[256];
        }
    }
}

// ---------------------------------------------------------------------------
// conv[b][c][m] = sum_s part[s][b][c][m]  — 16 independent coalesced loads
// per thread, plain stores.
// ---------------------------------------------------------------------------
__global__ void reduce_kernel(const double* __restrict__ part, double* __restrict__ conv) {
    const int idx = blockIdx.x * 256 + threadIdx.x;
    if (idx >= B_ * 2 * M_) return;
    const int b  = idx / (2 * M_);
    const int rm = idx - b * 2 * M_;       // c*M_ + m
    const int c  = rm / M_;
    const int m  = rm - c * M_;
    const size_t off = ((size_t)b * 2 + c) * MPAD + m;
    const size_t sstride = (size_t)B_ * 2 * MPAD;
    double acc = 0.0;
    #pragma unroll
    for (int k = 0; k < CV_SPLIT; ++k)
        acc += part[(size_t)k * sstride + off];
    conv[idx] = acc;
}

// ---------------------------------------------------------------------------
// fmm[b][n][c] = (1/M) sum_m g[b,n,m] * conv[b][c][m]
// FMM_LPP lanes per point; contiguous window reads; shfl-xor reduce.
// ---------------------------------------------------------------------------
__global__ void fmm_kernel(const float* __restrict__ x, const double* __restrict__ conv,
                           float* __restrict__ out) {
    const int gid = blockIdx.x * 256 + threadIdx.x;
    const int pt  = gid / FMM_LPP;     // point id = b*N + n
    const int sub = gid % FMM_LPP;
    const int b   = pt >> 10;          // / N_
    const double du      = TWO_PI_ / (double)M_;
    const double inv4tau = 1.0 / (4.0 * TAU_);
    const double u = (double)x[pt] * (TWO_PI_ / 10.0);
    int mc = (int)(u / du + 0.5);
    int lo = mc - 34; if (lo < 0) lo = 0;
    int hi = mc + 34; if (hi > M_ - 1) hi = M_ - 1;
    const double* c0 = conv + (size_t)(b * 2) * M_;
    const double* c1 = c0 + M_;
    double a0 = 0.0, a1 = 0.0;
    for (int m = lo + sub; m <= hi; m += FMM_LPP) {
        double d = u - du * (double)m;
        double g = (double)__expf(-(float)(d * d * inv4tau));
        a0 += g * c0[m];
        a1 += g * c1[m];
    }
    a0 += __shfl_xor(a0, 1); a1 += __shfl_xor(a1, 1);
    a0 += __shfl_xor(a0, 2); a1 += __shfl_xor(a1, 2);
    a0 += __shfl_xor(a0, 4); a1 += __shfl_xor(a1, 4);
    a0 += __shfl_xor(a0, 8); a1 += __shfl_xor(a1, 8);
    if (sub == 0) {
        out[pt * 2 + 0] = (float)(a0 / (double)M_);
        out[pt * 2 + 1] = (float)(a1 / (double)M_);
    }
}

// ---------------------------------------------------------------------------
extern "C" void kernel_launch(void* const* d_in, const int* in_sizes, int n_in,
                              void* d_out, int out_size, void* d_ws, size_t ws_size,
                              hipStream_t stream) {
    (void)in_sizes; (void)n_in; (void)out_size; (void)ws_size;
    const float* x  = (const float*)d_in[0];
    const float* s0 = (const float*)d_in[1];
    const float* a0 = (const float*)d_in[2];
    const float* s1 = (const float*)d_in[3];
    const float* a1 = (const float*)d_in[4];
    float* out = (float*)d_out;

    // Workspace layout (f64): [gsum B*M | hhalf 2*1025 | conv B*2*M | part]
    double* gsum  = (double*)d_ws;             // 32784
    double* hhalf = gsum + B_ * M_;            // 2050
    double* conv  = hhalf + 2 * 1025;          // 65568
    double* part  = conv + B_ * 2 * M_;        // CV_SPLIT*B_*2*MPAD = 1050624 (~8.4 MB)

    // Zero only the atomic-accumulated regions (gsum + hhalf, ~278 KB)
    hipMemsetAsync(d_ws, 0, (size_t)(B_ * M_ + 2 * 1025) * sizeof(double), stream);

    hipLaunchKernelGGL(spread_h_kernel, dim3(GS_CH * B_ + 5 * H_JSPLIT), dim3(256), 0,
                       stream, x, s0, a0, s1, a1, gsum, hhalf);
    hipLaunchKernelGGL(conv_kernel, dim3(2, CV_SPLIT, B_), dim3(256), 0, stream,
                       gsum, hhalf, part);
    hipLaunchKernelGGL(reduce_kernel, dim3((B_ * 2 * M_ + 255) / 256), dim3(256), 0, stream,
                       part, conv);
    hipLaunchKernelGGL(fmm_kernel, dim3(B_ * N_ * FMM_LPP / 256), dim3(256), 0, stream,
                       x, conv, out);
}